// Round 6
// baseline (488.433 us; speedup 1.0000x reference)
//
#include <hip/hip_runtime.h>

#define DF 64
#define BSH 8              // bucket = dst >> 8  (256 dst per bucket)
#define BW  256
#define PADCAP 768         // per-bucket extra pk2 capacity: 256 dst * 3 pad max

typedef unsigned short u16;
typedef unsigned int u32;
typedef __attribute__((ext_vector_type(8))) short short8;
typedef __attribute__((ext_vector_type(4))) float f32x4;

__device__ __forceinline__ float bf2f(u16 u) { return __uint_as_float(((u32)u) << 16); }
__device__ __forceinline__ u16 f2bf(float f) {
  u32 v = __float_as_uint(f);
  return (u16)((v + 0x7FFFu + ((v >> 16) & 1u)) >> 16);
}

// ============== bucket-sort CSR build (atomic-free globals) ==============

__global__ __launch_bounds__(256) void prehist(const int* __restrict__ ei,
                                               int* __restrict__ gh, int E, int NB) {
  __shared__ int lh[512];
  for (int t = threadIdx.x; t < NB; t += 256) lh[t] = 0;
  __syncthreads();
  int e0 = blockIdx.x * 1024;
#pragma unroll
  for (int j = 0; j < 4; j++) {
    int e = e0 + j * 256 + threadIdx.x;
    if (e < E) atomicAdd(&lh[ei[E + e] >> BSH], 1);
  }
  __syncthreads();
  for (int t = threadIdx.x; t < NB; t += 256)
    gh[(size_t)blockIdx.x * NB + t] = lh[t];
}

__global__ __launch_bounds__(256) void scanA(int* __restrict__ gh, int* __restrict__ btot,
                                             int nblk, int NB) {
  int c = blockIdx.x;
  __shared__ int sc[256];
  int carry = 0;
  for (int b0 = 0; b0 < nblk; b0 += 256) {
    int b = b0 + threadIdx.x;
    int orig = (b < nblk) ? gh[(size_t)b * NB + c] : 0;
    int v = orig;
    sc[threadIdx.x] = v;
    __syncthreads();
    for (int off = 1; off < 256; off <<= 1) {
      int o = threadIdx.x >= off ? sc[threadIdx.x - off] : 0;
      __syncthreads();
      v += o;
      sc[threadIdx.x] = v;
      __syncthreads();
    }
    int ctot = sc[255];
    if (b < nblk) gh[(size_t)b * NB + c] = carry + v - orig;
    carry += ctot;
    __syncthreads();
  }
  if (threadIdx.x == 0) btot[c] = carry;
}

__global__ __launch_bounds__(256) void scanB(const int* __restrict__ btot,
                                             int* __restrict__ bstart,
                                             int* __restrict__ rowptr, int NB, int n, int E) {
  __shared__ int sc[256];
  int base = threadIdx.x * 4;
  int c[4], s = 0;
#pragma unroll
  for (int j = 0; j < 4; j++) {
    int idx = base + j;
    c[j] = idx < NB ? btot[idx] : 0;
    s += c[j];
  }
  int v = s;
  sc[threadIdx.x] = v;
  __syncthreads();
  for (int off = 1; off < 256; off <<= 1) {
    int o = threadIdx.x >= off ? sc[threadIdx.x - off] : 0;
    __syncthreads();
    v += o;
    sc[threadIdx.x] = v;
    __syncthreads();
  }
  int run = v - s;
#pragma unroll
  for (int j = 0; j < 4; j++) {
    int idx = base + j;
    if (idx <= NB) bstart[idx] = run;
    run += c[j];
  }
}

// bin edges into dst-buckets; 8B records {dl | src<<8, w_fp32}
__global__ __launch_bounds__(256) void pass1(const int* __restrict__ ei,
                                             const float* __restrict__ w,
                                             const int* __restrict__ gh,
                                             const int* __restrict__ bstart,
                                             int2* __restrict__ pk1, int E, int NB) {
  __shared__ int lh[512];
  __shared__ int lbase[512];
  for (int t = threadIdx.x; t < NB; t += 256) lh[t] = 0;
  __syncthreads();
  int e0 = blockIdx.x * 1024;
  int s[4], d[4], r[4];
  float wv[4];
#pragma unroll
  for (int j = 0; j < 4; j++) {
    int e = e0 + j * 256 + threadIdx.x;
    if (e < E) {
      s[j] = ei[e];
      d[j] = ei[E + e];
      wv[j] = w[e];
      r[j] = atomicAdd(&lh[d[j] >> BSH], 1);
    }
  }
  __syncthreads();
  for (int t = threadIdx.x; t < NB; t += 256)
    lbase[t] = bstart[t] + gh[(size_t)blockIdx.x * NB + t];
  __syncthreads();
#pragma unroll
  for (int j = 0; j < 4; j++) {
    int e = e0 + j * 256 + threadIdx.x;
    if (e < E)
      pk1[lbase[d[j] >> BSH] + r[j]] =
          make_int2((d[j] & 255) | (s[j] << 8), __float_as_int(wv[j]));
  }
}

// per-bucket counting sort (LDS) -> pk2 {src | dl<<17, w_fp32}; per-row counts padded
// to a multiple of 4 with {src=self, w=0} records so 4-edge steps never straddle rows.
// Emits dinv, PADDED per-node rowptr, and per-bucket padded end (bendp).
__global__ __launch_bounds__(256) void pass2(const int2* __restrict__ pk1,
                                             const int* __restrict__ bstart,
                                             int2* __restrict__ pk2,
                                             float* __restrict__ dinv,
                                             int* __restrict__ rowptr,
                                             int* __restrict__ bendp, int n) {
  int c = blockIdx.x;
  int dbase = c << BSH;
  __shared__ int h[BW];
  __shared__ float dg[BW];
  __shared__ int sc[BW];
  __shared__ int cur[BW];
  h[threadIdx.x] = 0;
  dg[threadIdx.x] = 0.f;
  __syncthreads();
  int e0 = bstart[c], e1 = bstart[c + 1];
  for (int e = e0 + threadIdx.x; e < e1; e += 256) {
    int2 p = pk1[e];
    int dl = p.x & 255;
    atomicAdd(&h[dl], 1);
    atomicAdd(&dg[dl], __int_as_float(p.y));
  }
  __syncthreads();
  int own = h[threadIdx.x];
  int hp = (own + 3) & ~3;           // padded count
  int v = hp;
  sc[threadIdx.x] = v;
  __syncthreads();
  for (int off = 1; off < 256; off <<= 1) {
    int o = threadIdx.x >= off ? sc[threadIdx.x - off] : 0;
    __syncthreads();
    v += o;
    sc[threadIdx.x] = v;
    __syncthreads();
  }
  int e0p = e0 + c * PADCAP;          // padded bucket base (capacity layout)
  int startp = e0p + v - hp;          // padded per-dst start
  cur[threadIdx.x] = startp;
  int i = dbase + threadIdx.x;
  if (i < n) dinv[i] = rsqrtf(dg[threadIdx.x] + 1.0f);   // self-loop +1
  if (i <= n) rowptr[i] = startp;                         // PADDED per-node CSR pointer
  if (threadIdx.x == 255) bendp[c] = e0p + v;             // padded bucket end
  __syncthreads();
  for (int e = e0 + threadIdx.x; e < e1; e += 256) {
    int2 p = pk1[e];
    int dl = p.x & 255;
    int slot = atomicAdd(&cur[dl], 1);
    pk2[slot] = make_int2((p.x >> 8) | (dl << 17), p.y);
  }
  // pad records: src = self (cache-hot), weight 0
  int npad = hp - own;
  for (int k = 0; k < npad; k++)
    pk2[startp + own + k] = make_int2(i | (threadIdx.x << 17), 0);
}

// ================= compute =================

// B fragment for MFMA 16x16x32: B[k = k0+j][col], bf16-RNE from fp32 W
__device__ __forceinline__ short8 bfrag(const float* __restrict__ W, int k0, int col) {
  short8 b;
#pragma unroll
  for (int j = 0; j < 8; j++) b[j] = (short)f2bf(W[(k0 + j) * DF + col]);
  return b;
}

// MFMA GEMM: xl' = bf16( (bf16(A) @ bf16(W)) * dinv_row ), written SLICE-MAJOR:
// xs[slice=ft][row][feat m] so each 16-feature slice is a contiguous 3.2 MB block.
__global__ __launch_bounds__(256) void gemm_init(const float* __restrict__ A,
                                                 const float* __restrict__ W,
                                                 const float* __restrict__ dinv,
                                                 u16* __restrict__ xl, int n, int tiles,
                                                 int nstr) {
  int lane = threadIdx.x & 63;
  int m = lane & 15, quad = lane >> 4;
  int wid = blockIdx.x * 4 + (threadIdx.x >> 6);
  int nw = gridDim.x * 4;
  short8 B0[4], B1[4];
#pragma unroll
  for (int ft = 0; ft < 4; ft++) {
    B0[ft] = bfrag(W, quad * 8, ft * 16 + m);
    B1[ft] = bfrag(W, 32 + quad * 8, ft * 16 + m);
  }
  for (int t = wid; t < tiles; t += nw) {
    int row0 = t * 16;
    int r = row0 + m;
    if (r >= n) r = n - 1;
    const float* ap = A + (size_t)r * DF + quad * 8;
    float4 u0 = *(const float4*)ap;
    float4 u1 = *(const float4*)(ap + 4);
    float4 u2 = *(const float4*)(ap + 32);
    float4 u3 = *(const float4*)(ap + 36);
    short8 a0, a1;
    a0[0]=(short)f2bf(u0.x); a0[1]=(short)f2bf(u0.y); a0[2]=(short)f2bf(u0.z); a0[3]=(short)f2bf(u0.w);
    a0[4]=(short)f2bf(u1.x); a0[5]=(short)f2bf(u1.y); a0[6]=(short)f2bf(u1.z); a0[7]=(short)f2bf(u1.w);
    a1[0]=(short)f2bf(u2.x); a1[1]=(short)f2bf(u2.y); a1[2]=(short)f2bf(u2.z); a1[3]=(short)f2bf(u2.w);
    a1[4]=(short)f2bf(u3.x); a1[5]=(short)f2bf(u3.y); a1[6]=(short)f2bf(u3.z); a1[7]=(short)f2bf(u3.w);
    f32x4 c[4];
#pragma unroll
    for (int ft = 0; ft < 4; ft++) c[ft] = (f32x4){0.f, 0.f, 0.f, 0.f};
#pragma unroll
    for (int ft = 0; ft < 4; ft++) {
      c[ft] = __builtin_amdgcn_mfma_f32_16x16x32_bf16(a0, B0[ft], c[ft], 0, 0, 0);
      c[ft] = __builtin_amdgcn_mfma_f32_16x16x32_bf16(a1, B1[ft], c[ft], 0, 0, 0);
    }
    float dd[4];
#pragma unroll
    for (int reg = 0; reg < 4; reg++) {
      int r2 = row0 + quad * 4 + reg;
      dd[reg] = (r2 < n) ? dinv[r2] : 0.f;
    }
#pragma unroll
    for (int ft = 0; ft < 4; ft++)
#pragma unroll
      for (int reg = 0; reg < 4; reg++) {
        int r2 = row0 + quad * 4 + reg;
        if (r2 < n)
          xl[(size_t)ft * nstr + (size_t)r2 * 16 + m] = f2bf(c[ft][reg] * dd[reg]);
      }
  }
}

// MFMA GEMM with BN+PReLU fused into A-load; same slice-major dinv-folded output
__global__ __launch_bounds__(256) void gemm_bn_init(const float* __restrict__ accin,
                                                    const float* __restrict__ stats,
                                                    const float* __restrict__ alpha_p,
                                                    const float* __restrict__ W,
                                                    const float* __restrict__ dinv,
                                                    u16* __restrict__ xl, int n, int tiles,
                                                    int nstr) {
  int lane = threadIdx.x & 63;
  int m = lane & 15, quad = lane >> 4;
  int wid = blockIdx.x * 4 + (threadIdx.x >> 6);
  int nw = gridDim.x * 4;
  short8 B0[4], B1[4];
#pragma unroll
  for (int ft = 0; ft < 4; ft++) {
    B0[ft] = bfrag(W, quad * 8, ft * 16 + m);
    B1[ft] = bfrag(W, 32 + quad * 8, ft * 16 + m);
  }
  float s0[8], t0[8], s1[8], t1[8];
#pragma unroll
  for (int j = 0; j < 8; j++) {
    s0[j] = stats[128 + quad * 8 + j];
    t0[j] = stats[192 + quad * 8 + j];
    s1[j] = stats[128 + 32 + quad * 8 + j];
    t1[j] = stats[192 + 32 + quad * 8 + j];
  }
  float al = alpha_p[0];
  for (int t = wid; t < tiles; t += nw) {
    int row0 = t * 16;
    int r = row0 + m;
    if (r >= n) r = n - 1;
    const float* ap = accin + (size_t)r * DF + quad * 8;
    float h0[8], h1[8];
#pragma unroll
    for (int j = 0; j < 8; j++) { h0[j] = ap[j]; h1[j] = ap[32 + j]; }
    short8 a0, a1;
#pragma unroll
    for (int j = 0; j < 8; j++) {
      float y0 = h0[j] * s0[j] + t0[j];
      y0 = (y0 >= 0.f) ? y0 : al * y0;
      a0[j] = (short)f2bf(y0);
      float y1 = h1[j] * s1[j] + t1[j];
      y1 = (y1 >= 0.f) ? y1 : al * y1;
      a1[j] = (short)f2bf(y1);
    }
    f32x4 c[4];
#pragma unroll
    for (int ft = 0; ft < 4; ft++) c[ft] = (f32x4){0.f, 0.f, 0.f, 0.f};
#pragma unroll
    for (int ft = 0; ft < 4; ft++) {
      c[ft] = __builtin_amdgcn_mfma_f32_16x16x32_bf16(a0, B0[ft], c[ft], 0, 0, 0);
      c[ft] = __builtin_amdgcn_mfma_f32_16x16x32_bf16(a1, B1[ft], c[ft], 0, 0, 0);
    }
    float dd[4];
#pragma unroll
    for (int reg = 0; reg < 4; reg++) {
      int r2 = row0 + quad * 4 + reg;
      dd[reg] = (r2 < n) ? dinv[r2] : 0.f;
    }
#pragma unroll
    for (int ft = 0; ft < 4; ft++)
#pragma unroll
      for (int reg = 0; reg < 4; reg++) {
        int r2 = row0 + quad * 4 + reg;
        if (r2 < n)
          xl[(size_t)ft * nstr + (size_t)r2 * 16 + m] = f2bf(c[ft][reg] * dd[reg]);
      }
  }
}

// XCD-team sliced aggregation: team = blockIdx&7 -> (slice s = t&3, row-half h = t>>2).
// Each team gathers only within its 3.2 MB feature slice (fits one XCD's 4 MB L2)
// and streams only its row-half's records (contiguous, dst-sorted). Lane map:
// slot g = lane>>4 (edge slot, edges ≡ g mod 4 — identical sum order to edge_agg6),
// feature m = lane&15. Counted per-row loop, flush once per row.
__global__ __launch_bounds__(256) void edge_agg7(const int2* __restrict__ pk,
                                                 const int* __restrict__ rowptr,
                                                 const int* __restrict__ bendp,
                                                 const u16* __restrict__ xl,
                                                 const float* __restrict__ dinv,
                                                 const float* __restrict__ bias,
                                                 float* __restrict__ acc,
                                                 float* __restrict__ statp,
                                                 int n, int nh, int nstr) {
  int lane = threadIdx.x & 63;
  int wsub = threadIdx.x >> 6;
  int team = blockIdx.x & 7;
  int blk  = blockIdx.x >> 3;
  int s    = team & 3;               // feature slice
  int h    = team >> 2;              // row half
  int g    = lane >> 4;              // edge slot
  int m    = lane & 15;              // feature within slice
  int fidx = s * 16 + m;
  const u16* __restrict__ xs = xl + (size_t)s * nstr;
  int rbase = h * nh;
  int rend  = min(rbase + nh, n);
  int ru = rbase + (blk * 4 + wsub) * 4;
  float bl = bias[fidx];
  float sm = 0.f, sq = 0.f;

  if (ru < rend) {
    int rmax = min(ru + 4, rend);
    for (int row = ru; row < rmax; row++) {
      int gs = __builtin_amdgcn_readfirstlane(rowptr[row]);
      int ge = (((row + 1) & 255) == 0)
                 ? __builtin_amdgcn_readfirstlane(bendp[row >> 8])
                 : __builtin_amdgcn_readfirstlane(rowptr[row + 1]);
      int steps = (ge - gs) >> 2;
      const int2* __restrict__ pw = pk + gs;
      float dv = dinv[row];
      float a = (g == 0) ? bf2f(xs[(size_t)row * 16 + m]) : 0.f;  // self-loop

      for (int s0 = 0; s0 < steps; s0 += 4) {
        int i1 = s0 + 1, i2 = s0 + 2, i3 = s0 + 3;
        int c1 = i1 < steps ? i1 : steps - 1;
        int c2 = i2 < steps ? i2 : steps - 1;
        int c3 = i3 < steps ? i3 : steps - 1;
        int2 rA = pw[s0 * 4 + g];
        int2 rB = pw[c1 * 4 + g];
        int2 rC = pw[c2 * 4 + g];
        int2 rD = pw[c3 * 4 + g];
        u16 gA = xs[((size_t)(u32)(rA.x & 0x1FFFF) << 4) + m];   // 32 B/slot, L2-hit
        u16 gB = xs[((size_t)(u32)(rB.x & 0x1FFFF) << 4) + m];
        u16 gC = xs[((size_t)(u32)(rC.x & 0x1FFFF) << 4) + m];
        u16 gD = xs[((size_t)(u32)(rD.x & 0x1FFFF) << 4) + m];
        float wA = __int_as_float(rA.y);                         // s0 always < steps
        float wB = (i1 < steps) ? __int_as_float(rB.y) : 0.f;    // clamped dupes: w=0
        float wC = (i2 < steps) ? __int_as_float(rC.y) : 0.f;
        float wD = (i3 < steps) ? __int_as_float(rD.y) : 0.f;
        a = fmaf(wA, bf2f(gA), a);
        a = fmaf(wB, bf2f(gB), a);
        a = fmaf(wC, bf2f(gC), a);
        a = fmaf(wD, bf2f(gD), a);
      }

      // flush: reduce over 4 slots (2 shuffle rounds), store 16 features (64 B)
      float r = a;
      r += __shfl_xor(r, 16);
      r += __shfl_xor(r, 32);
      float v = fmaf(r, dv, bl);
      if (g == 0) {
        acc[((size_t)row << 6) + fidx] = v;
        sm += v;
        sq = fmaf(v, v, sq);
      }
    }
  }

  __shared__ float ls[4][DF], lss[4][DF];
  ls[wsub][lane] = 0.f;              // zero all features (team covers 16 of 64)
  lss[wsub][lane] = 0.f;
  if (g == 0) {                      // same-wave later write wins (program order)
    ls[wsub][fidx] = sm;
    lss[wsub][fidx] = sq;
  }
  __syncthreads();
  if (threadIdx.x < DF) {
    int fi = threadIdx.x;
    float t1 = ls[0][fi] + ls[1][fi] + ls[2][fi] + ls[3][fi];
    float t2 = lss[0][fi] + lss[1][fi] + lss[2][fi] + lss[3][fi];
    int slot = (blockIdx.x & 63) * 128;   // 64-way spread kills same-line contention
    unsafeAtomicAdd(&statp[slot + fi], t1);
    unsafeAtomicAdd(&statp[slot + DF + fi], t2);
  }
}

__global__ void finalize_stats(const float* __restrict__ statp, float* __restrict__ stats,
                               const float* __restrict__ gamma,
                               const float* __restrict__ beta, int n) {
  int f = threadIdx.x;
  if (f >= DF) return;
  float s = 0.f, ss = 0.f;
#pragma unroll 4
  for (int c = 0; c < 64; c++) {
    s += statp[c * 128 + f];
    ss += statp[c * 128 + DF + f];
  }
  float mean = s / n;
  float var = ss / n - mean * mean;
  float rstd = rsqrtf(var + 1e-5f);
  float sc = gamma[f] * rstd;
  stats[128 + f] = sc;
  stats[192 + f] = beta[f] - mean * sc;
}

__global__ void bnapply(const float* __restrict__ acc, const float* __restrict__ stats,
                        const float* __restrict__ alpha_p, float* __restrict__ outb, int n) {
  int i = blockIdx.x * 4 + (threadIdx.x >> 6);
  if (i >= n) return;
  int f = threadIdx.x & 63;
  float y = acc[(size_t)i * DF + f] * stats[128 + f] + stats[192 + f];
  float a = alpha_p[0];
  y = (y >= 0.f) ? y : a * y;
  outb[(size_t)i * DF + f] = y;
}

extern "C" void kernel_launch(void* const* d_in, const int* in_sizes, int n_in,
                              void* d_out, int out_size, void* d_ws, size_t ws_size,
                              hipStream_t stream) {
  const float* x  = (const float*)d_in[0];
  const int* ei   = (const int*)d_in[1];
  const float* w  = (const float*)d_in[2];
  const float* W1 = (const float*)d_in[3];
  const float* b1 = (const float*)d_in[4];
  const float* g1 = (const float*)d_in[5];
  const float* be1= (const float*)d_in[6];
  const float* al1= (const float*)d_in[7];
  const float* W2 = (const float*)d_in[8];
  const float* b2 = (const float*)d_in[9];
  const float* g2 = (const float*)d_in[10];
  const float* be2= (const float*)d_in[11];
  const float* al2= (const float*)d_in[12];
  float* out = (float*)d_out;

  const int n = in_sizes[0] / DF;
  const int E = in_sizes[2];
  const size_t na = ((size_t)n + 255) & ~(size_t)255;
  const int NB = (n + BW - 1) >> BSH;
  const int nblk1 = (E + 1023) / 1024;
  const size_t ghsz = (((size_t)nblk1 * NB) + 3) & ~(size_t)3;
  const int tiles = (n + 15) / 16;
  const size_t pk2cap = (size_t)E + (size_t)NB * PADCAP + 64;
  const int nstr = (int)(na * 16);            // u16 units per feature slice
  const int nh = (n + 1) / 2;                 // rows per half

  // ---- workspace layout (4-byte units; int2 arrays 8B-aligned) ----
  float* wsf = (float*)d_ws;
  float* stats1 = wsf;                          // 256
  float* stats2 = stats1 + 256;                 // 256
  float* statp1 = stats2 + 256;                 // 8192 (64 spread copies x 128)
  float* statp2 = statp1 + 8192;                // 8192
  int*   btot   = (int*)(statp2 + 8192);        // 512
  int*   bstart = btot + 512;                   // 512 (NB+1 used)
  int*   bendp  = bstart + 512;                 // 512 (NB used)
  int*   rowptr = bendp + 512;                  // na + 4 (n+1 used)
  float* dinv   = (float*)(rowptr + na + 4);    // na
  int*   gh     = (int*)(dinv + na);            // ghsz
  int2*  pk2    = (int2*)(gh + ghsz);           // pk2cap records (8B each, padded CSR)
  int*   U      = (int*)(pk2 + pk2cap);         // overlay: pk1 (2E) | XL16+ACC
  int2*  pk1    = (int2*)U;
  u16*   XL16   = (u16*)U;                      // na*64 bf16, slice-major (after pass2)
  float* ACC    = (float*)(U + na * 32);        // na*64 fp32

  const int nb_nodes = (n + 3) / 4;
  const int nb_gemm  = 512;
  const int nb_agg   = ((nh + 15) / 16) * 8;    // 8 teams x row-blocks (16 rows each)

  hipMemsetAsync(stats1, 0, (512 + 16384) * sizeof(float), stream);

  // ---- CSR build (bucket sort, 8B records, padded per-node rowptr) ----
  prehist<<<nblk1, 256, 0, stream>>>(ei, gh, E, NB);
  scanA<<<NB, 256, 0, stream>>>(gh, btot, nblk1, NB);
  scanB<<<1, 256, 0, stream>>>(btot, bstart, rowptr, NB, n, E);
  pass1<<<nblk1, 256, 0, stream>>>(ei, w, gh, bstart, pk1, E, NB);
  pass2<<<NB, 256, 0, stream>>>(pk1, bstart, pk2, dinv, rowptr, bendp, n);

  // ---- layer 1 ----
  gemm_init<<<nb_gemm, 256, 0, stream>>>(x, W1, dinv, XL16, n, tiles, nstr);
  edge_agg7<<<nb_agg, 256, 0, stream>>>(pk2, rowptr, bendp, XL16, dinv, b1, ACC, statp1, n, nh, nstr);
  finalize_stats<<<1, 64, 0, stream>>>(statp1, stats1, g1, be1, n);

  // ---- layer 2 ----
  gemm_bn_init<<<nb_gemm, 256, 0, stream>>>(ACC, stats1, al1, W2, dinv, XL16, n, tiles, nstr);
  edge_agg7<<<nb_agg, 256, 0, stream>>>(pk2, rowptr, bendp, XL16, dinv, b2, ACC, statp2, n, nh, nstr);
  finalize_stats<<<1, 64, 0, stream>>>(statp2, stats2, g2, be2, n);
  bnapply<<<nb_nodes, 256, 0, stream>>>(ACC, stats2, al2, out, n);
}

// Round 7
// 333.755 us; speedup vs baseline: 1.4634x; 1.4634x over previous
//
#include <hip/hip_runtime.h>

#define DF 64
#define BSH 8              // bucket = dst >> 8  (256 dst per bucket)
#define BW  256
#define PADCAP 768         // per-bucket extra pk2 capacity: 256 dst * 3 pad max

typedef unsigned short u16;
typedef unsigned int u32;
typedef __attribute__((ext_vector_type(8))) short short8;
typedef __attribute__((ext_vector_type(4))) float f32x4;

__device__ __forceinline__ float bf2f(u16 u) { return __uint_as_float(((u32)u) << 16); }
__device__ __forceinline__ u16 f2bf(float f) {
  u32 v = __float_as_uint(f);
  return (u16)((v + 0x7FFFu + ((v >> 16) & 1u)) >> 16);
}

// ============== bucket-sort CSR build (atomic-free globals) ==============

__global__ __launch_bounds__(256) void prehist(const int* __restrict__ ei,
                                               int* __restrict__ gh, int E, int NB) {
  __shared__ int lh[512];
  for (int t = threadIdx.x; t < NB; t += 256) lh[t] = 0;
  __syncthreads();
  int e0 = blockIdx.x * 1024;
#pragma unroll
  for (int j = 0; j < 4; j++) {
    int e = e0 + j * 256 + threadIdx.x;
    if (e < E) atomicAdd(&lh[ei[E + e] >> BSH], 1);
  }
  __syncthreads();
  for (int t = threadIdx.x; t < NB; t += 256)
    gh[(size_t)blockIdx.x * NB + t] = lh[t];
}

__global__ __launch_bounds__(256) void scanA(int* __restrict__ gh, int* __restrict__ btot,
                                             int nblk, int NB) {
  int c = blockIdx.x;
  __shared__ int sc[256];
  int carry = 0;
  for (int b0 = 0; b0 < nblk; b0 += 256) {
    int b = b0 + threadIdx.x;
    int orig = (b < nblk) ? gh[(size_t)b * NB + c] : 0;
    int v = orig;
    sc[threadIdx.x] = v;
    __syncthreads();
    for (int off = 1; off < 256; off <<= 1) {
      int o = threadIdx.x >= off ? sc[threadIdx.x - off] : 0;
      __syncthreads();
      v += o;
      sc[threadIdx.x] = v;
      __syncthreads();
    }
    int ctot = sc[255];
    if (b < nblk) gh[(size_t)b * NB + c] = carry + v - orig;
    carry += ctot;
    __syncthreads();
  }
  if (threadIdx.x == 0) btot[c] = carry;
}

__global__ __launch_bounds__(256) void scanB(const int* __restrict__ btot,
                                             int* __restrict__ bstart,
                                             int* __restrict__ rowptr, int NB, int n, int E) {
  __shared__ int sc[256];
  int base = threadIdx.x * 4;
  int c[4], s = 0;
#pragma unroll
  for (int j = 0; j < 4; j++) {
    int idx = base + j;
    c[j] = idx < NB ? btot[idx] : 0;
    s += c[j];
  }
  int v = s;
  sc[threadIdx.x] = v;
  __syncthreads();
  for (int off = 1; off < 256; off <<= 1) {
    int o = threadIdx.x >= off ? sc[threadIdx.x - off] : 0;
    __syncthreads();
    v += o;
    sc[threadIdx.x] = v;
    __syncthreads();
  }
  int run = v - s;
#pragma unroll
  for (int j = 0; j < 4; j++) {
    int idx = base + j;
    if (idx <= NB) bstart[idx] = run;
    run += c[j];
  }
}

// bin edges into dst-buckets; 8B records {dl | src<<8, w_fp32}
__global__ __launch_bounds__(256) void pass1(const int* __restrict__ ei,
                                             const float* __restrict__ w,
                                             const int* __restrict__ gh,
                                             const int* __restrict__ bstart,
                                             int2* __restrict__ pk1, int E, int NB) {
  __shared__ int lh[512];
  __shared__ int lbase[512];
  for (int t = threadIdx.x; t < NB; t += 256) lh[t] = 0;
  __syncthreads();
  int e0 = blockIdx.x * 1024;
  int s[4], d[4], r[4];
  float wv[4];
#pragma unroll
  for (int j = 0; j < 4; j++) {
    int e = e0 + j * 256 + threadIdx.x;
    if (e < E) {
      s[j] = ei[e];
      d[j] = ei[E + e];
      wv[j] = w[e];
      r[j] = atomicAdd(&lh[d[j] >> BSH], 1);
    }
  }
  __syncthreads();
  for (int t = threadIdx.x; t < NB; t += 256)
    lbase[t] = bstart[t] + gh[(size_t)blockIdx.x * NB + t];
  __syncthreads();
#pragma unroll
  for (int j = 0; j < 4; j++) {
    int e = e0 + j * 256 + threadIdx.x;
    if (e < E)
      pk1[lbase[d[j] >> BSH] + r[j]] =
          make_int2((d[j] & 255) | (s[j] << 8), __float_as_int(wv[j]));
  }
}

// per-bucket counting sort (LDS) -> pk2 {src | dl<<17, w_fp32}; per-row counts padded
// to a multiple of 4 with {src=self, w=0} records so 4-edge steps never straddle rows.
// Emits dinv, PADDED per-node rowptr, and per-bucket padded end (bendp).
__global__ __launch_bounds__(256) void pass2(const int2* __restrict__ pk1,
                                             const int* __restrict__ bstart,
                                             int2* __restrict__ pk2,
                                             float* __restrict__ dinv,
                                             int* __restrict__ rowptr,
                                             int* __restrict__ bendp, int n) {
  int c = blockIdx.x;
  int dbase = c << BSH;
  __shared__ int h[BW];
  __shared__ float dg[BW];
  __shared__ int sc[BW];
  __shared__ int cur[BW];
  h[threadIdx.x] = 0;
  dg[threadIdx.x] = 0.f;
  __syncthreads();
  int e0 = bstart[c], e1 = bstart[c + 1];
  for (int e = e0 + threadIdx.x; e < e1; e += 256) {
    int2 p = pk1[e];
    int dl = p.x & 255;
    atomicAdd(&h[dl], 1);
    atomicAdd(&dg[dl], __int_as_float(p.y));
  }
  __syncthreads();
  int own = h[threadIdx.x];
  int hp = (own + 3) & ~3;           // padded count
  int v = hp;
  sc[threadIdx.x] = v;
  __syncthreads();
  for (int off = 1; off < 256; off <<= 1) {
    int o = threadIdx.x >= off ? sc[threadIdx.x - off] : 0;
    __syncthreads();
    v += o;
    sc[threadIdx.x] = v;
    __syncthreads();
  }
  int e0p = e0 + c * PADCAP;          // padded bucket base (capacity layout)
  int startp = e0p + v - hp;          // padded per-dst start
  cur[threadIdx.x] = startp;
  int i = dbase + threadIdx.x;
  if (i < n) dinv[i] = rsqrtf(dg[threadIdx.x] + 1.0f);   // self-loop +1
  if (i <= n) rowptr[i] = startp;                         // PADDED per-node CSR pointer
  if (threadIdx.x == 255) bendp[c] = e0p + v;             // padded bucket end
  __syncthreads();
  for (int e = e0 + threadIdx.x; e < e1; e += 256) {
    int2 p = pk1[e];
    int dl = p.x & 255;
    int slot = atomicAdd(&cur[dl], 1);
    pk2[slot] = make_int2((p.x >> 8) | (dl << 17), p.y);
  }
  // pad records: src = self (cache-hot), weight 0
  int npad = hp - own;
  for (int k = 0; k < npad; k++)
    pk2[startp + own + k] = make_int2(i | (threadIdx.x << 17), 0);
}

// ================= compute =================

// B fragment for MFMA 16x16x32: B[k = k0+j][col], bf16-RNE from fp32 W
__device__ __forceinline__ short8 bfrag(const float* __restrict__ W, int k0, int col) {
  short8 b;
#pragma unroll
  for (int j = 0; j < 8; j++) b[j] = (short)f2bf(W[(k0 + j) * DF + col]);
  return b;
}

// MFMA GEMM: xl' = bf16( (bf16(A) @ bf16(W)) * dinv_row )   (src-side dinv folded in)
__global__ __launch_bounds__(256) void gemm_init(const float* __restrict__ A,
                                                 const float* __restrict__ W,
                                                 const float* __restrict__ dinv,
                                                 u16* __restrict__ xl, int n, int tiles) {
  int lane = threadIdx.x & 63;
  int m = lane & 15, quad = lane >> 4;
  int wid = blockIdx.x * 4 + (threadIdx.x >> 6);
  int nw = gridDim.x * 4;
  short8 B0[4], B1[4];
#pragma unroll
  for (int ft = 0; ft < 4; ft++) {
    B0[ft] = bfrag(W, quad * 8, ft * 16 + m);
    B1[ft] = bfrag(W, 32 + quad * 8, ft * 16 + m);
  }
  for (int t = wid; t < tiles; t += nw) {
    int row0 = t * 16;
    int r = row0 + m;
    if (r >= n) r = n - 1;
    const float* ap = A + (size_t)r * DF + quad * 8;
    float4 u0 = *(const float4*)ap;
    float4 u1 = *(const float4*)(ap + 4);
    float4 u2 = *(const float4*)(ap + 32);
    float4 u3 = *(const float4*)(ap + 36);
    short8 a0, a1;
    a0[0]=(short)f2bf(u0.x); a0[1]=(short)f2bf(u0.y); a0[2]=(short)f2bf(u0.z); a0[3]=(short)f2bf(u0.w);
    a0[4]=(short)f2bf(u1.x); a0[5]=(short)f2bf(u1.y); a0[6]=(short)f2bf(u1.z); a0[7]=(short)f2bf(u1.w);
    a1[0]=(short)f2bf(u2.x); a1[1]=(short)f2bf(u2.y); a1[2]=(short)f2bf(u2.z); a1[3]=(short)f2bf(u2.w);
    a1[4]=(short)f2bf(u3.x); a1[5]=(short)f2bf(u3.y); a1[6]=(short)f2bf(u3.z); a1[7]=(short)f2bf(u3.w);
    f32x4 c[4];
#pragma unroll
    for (int ft = 0; ft < 4; ft++) c[ft] = (f32x4){0.f, 0.f, 0.f, 0.f};
#pragma unroll
    for (int ft = 0; ft < 4; ft++) {
      c[ft] = __builtin_amdgcn_mfma_f32_16x16x32_bf16(a0, B0[ft], c[ft], 0, 0, 0);
      c[ft] = __builtin_amdgcn_mfma_f32_16x16x32_bf16(a1, B1[ft], c[ft], 0, 0, 0);
    }
    float dd[4];
#pragma unroll
    for (int reg = 0; reg < 4; reg++) {
      int r2 = row0 + quad * 4 + reg;
      dd[reg] = (r2 < n) ? dinv[r2] : 0.f;
    }
#pragma unroll
    for (int ft = 0; ft < 4; ft++)
#pragma unroll
      for (int reg = 0; reg < 4; reg++) {
        int r2 = row0 + quad * 4 + reg;
        if (r2 < n)
          xl[(size_t)r2 * DF + ft * 16 + m] = f2bf(c[ft][reg] * dd[reg]);
      }
  }
}

// MFMA GEMM with BN+PReLU fused into A-load; same dinv-folded bf16 output
__global__ __launch_bounds__(256) void gemm_bn_init(const float* __restrict__ accin,
                                                    const float* __restrict__ stats,
                                                    const float* __restrict__ alpha_p,
                                                    const float* __restrict__ W,
                                                    const float* __restrict__ dinv,
                                                    u16* __restrict__ xl, int n, int tiles) {
  int lane = threadIdx.x & 63;
  int m = lane & 15, quad = lane >> 4;
  int wid = blockIdx.x * 4 + (threadIdx.x >> 6);
  int nw = gridDim.x * 4;
  short8 B0[4], B1[4];
#pragma unroll
  for (int ft = 0; ft < 4; ft++) {
    B0[ft] = bfrag(W, quad * 8, ft * 16 + m);
    B1[ft] = bfrag(W, 32 + quad * 8, ft * 16 + m);
  }
  float s0[8], t0[8], s1[8], t1[8];
#pragma unroll
  for (int j = 0; j < 8; j++) {
    s0[j] = stats[128 + quad * 8 + j];
    t0[j] = stats[192 + quad * 8 + j];
    s1[j] = stats[128 + 32 + quad * 8 + j];
    t1[j] = stats[192 + 32 + quad * 8 + j];
  }
  float al = alpha_p[0];
  for (int t = wid; t < tiles; t += nw) {
    int row0 = t * 16;
    int r = row0 + m;
    if (r >= n) r = n - 1;
    const float* ap = accin + (size_t)r * DF + quad * 8;
    float h0[8], h1[8];
#pragma unroll
    for (int j = 0; j < 8; j++) { h0[j] = ap[j]; h1[j] = ap[32 + j]; }
    short8 a0, a1;
#pragma unroll
    for (int j = 0; j < 8; j++) {
      float y0 = h0[j] * s0[j] + t0[j];
      y0 = (y0 >= 0.f) ? y0 : al * y0;
      a0[j] = (short)f2bf(y0);
      float y1 = h1[j] * s1[j] + t1[j];
      y1 = (y1 >= 0.f) ? y1 : al * y1;
      a1[j] = (short)f2bf(y1);
    }
    f32x4 c[4];
#pragma unroll
    for (int ft = 0; ft < 4; ft++) c[ft] = (f32x4){0.f, 0.f, 0.f, 0.f};
#pragma unroll
    for (int ft = 0; ft < 4; ft++) {
      c[ft] = __builtin_amdgcn_mfma_f32_16x16x32_bf16(a0, B0[ft], c[ft], 0, 0, 0);
      c[ft] = __builtin_amdgcn_mfma_f32_16x16x32_bf16(a1, B1[ft], c[ft], 0, 0, 0);
    }
    float dd[4];
#pragma unroll
    for (int reg = 0; reg < 4; reg++) {
      int r2 = row0 + quad * 4 + reg;
      dd[reg] = (r2 < n) ? dinv[r2] : 0.f;
    }
#pragma unroll
    for (int ft = 0; ft < 4; ft++)
#pragma unroll
      for (int reg = 0; reg < 4; reg++) {
        int r2 = row0 + quad * 4 + reg;
        if (r2 < n)
          xl[(size_t)r2 * DF + ft * 16 + m] = f2bf(c[ft][reg] * dd[reg]);
      }
  }
}

// owner-computes segmented aggregation, per-row counted inner loop:
// wave owns 4 rows; per row, steps = padded_edges/4 (exact, pass2 pads %4).
// Inner loop: 4 records + 4 four-line ushort4 gathers + 16 FMA — no row-boundary
// logic, no stores, no data-dependent control flow. Flush once per row.
__global__ __launch_bounds__(256) void edge_agg6(const int2* __restrict__ pk,
                                                 const int* __restrict__ rowptr,
                                                 const int* __restrict__ bendp,
                                                 const u16* __restrict__ xl,
                                                 const float* __restrict__ dinv,
                                                 const float* __restrict__ bias,
                                                 float* __restrict__ acc,
                                                 float* __restrict__ statp, int n) {
  int lane = threadIdx.x & 63;
  int wsub = threadIdx.x >> 6;
  int g = lane >> 4;                 // edge slot within a 4-edge step
  int fb = (lane & 15) * 4;          // feature base (4 features per lane)
  int ru = __builtin_amdgcn_readfirstlane((blockIdx.x * 4 + wsub) * 4);
  float bl0 = bias[fb], bl1 = bias[fb + 1], bl2 = bias[fb + 2], bl3 = bias[fb + 3];
  float sm0 = 0.f, sm1 = 0.f, sm2 = 0.f, sm3 = 0.f;
  float sq0 = 0.f, sq1 = 0.f, sq2 = 0.f, sq3 = 0.f;

  if (ru < n) {
    int rmax = min(ru + 4, n);
    for (int row = ru; row < rmax; row++) {
      int gs = __builtin_amdgcn_readfirstlane(rowptr[row]);
      int ge = (((row + 1) & 255) == 0)
                 ? __builtin_amdgcn_readfirstlane(bendp[row >> 8])
                 : __builtin_amdgcn_readfirstlane(rowptr[row + 1]);
      int steps = (ge - gs) >> 2;
      const int2* __restrict__ pw = pk + gs;
      float dv = dinv[row];
      ushort4 s4 = *(const ushort4*)(xl + ((size_t)row << 6) + fb);
      float a0 = (g == 0) ? bf2f(s4.x) : 0.f;   // self-loop: xl' already has dinv_d
      float a1 = (g == 0) ? bf2f(s4.y) : 0.f;
      float a2 = (g == 0) ? bf2f(s4.z) : 0.f;
      float a3 = (g == 0) ? bf2f(s4.w) : 0.f;

      for (int s0 = 0; s0 < steps; s0 += 4) {
        int i1 = s0 + 1, i2 = s0 + 2, i3 = s0 + 3;
        int c1 = i1 < steps ? i1 : steps - 1;
        int c2 = i2 < steps ? i2 : steps - 1;
        int c3 = i3 < steps ? i3 : steps - 1;
        int2 rA = pw[s0 * 4 + g];
        int2 rB = pw[c1 * 4 + g];
        int2 rC = pw[c2 * 4 + g];
        int2 rD = pw[c3 * 4 + g];
        ushort4 gA = *(const ushort4*)(xl + ((size_t)(u32)(rA.x & 0x1FFFF) << 6) + fb);
        ushort4 gB = *(const ushort4*)(xl + ((size_t)(u32)(rB.x & 0x1FFFF) << 6) + fb);
        ushort4 gC = *(const ushort4*)(xl + ((size_t)(u32)(rC.x & 0x1FFFF) << 6) + fb);
        ushort4 gD = *(const ushort4*)(xl + ((size_t)(u32)(rD.x & 0x1FFFF) << 6) + fb);
        float wA = __int_as_float(rA.y);                       // s0 always < steps
        float wB = (i1 < steps) ? __int_as_float(rB.y) : 0.f;  // clamped dupes: w=0
        float wC = (i2 < steps) ? __int_as_float(rC.y) : 0.f;
        float wD = (i3 < steps) ? __int_as_float(rD.y) : 0.f;
        a0 = fmaf(wA, bf2f(gA.x), a0); a1 = fmaf(wA, bf2f(gA.y), a1);
        a2 = fmaf(wA, bf2f(gA.z), a2); a3 = fmaf(wA, bf2f(gA.w), a3);
        a0 = fmaf(wB, bf2f(gB.x), a0); a1 = fmaf(wB, bf2f(gB.y), a1);
        a2 = fmaf(wB, bf2f(gB.z), a2); a3 = fmaf(wB, bf2f(gB.w), a3);
        a0 = fmaf(wC, bf2f(gC.x), a0); a1 = fmaf(wC, bf2f(gC.y), a1);
        a2 = fmaf(wC, bf2f(gC.z), a2); a3 = fmaf(wC, bf2f(gC.w), a3);
        a0 = fmaf(wD, bf2f(gD.x), a0); a1 = fmaf(wD, bf2f(gD.y), a1);
        a2 = fmaf(wD, bf2f(gD.z), a2); a3 = fmaf(wD, bf2f(gD.w), a3);
      }

      // flush: cross-group reduce (4 groups -> 2 shuffle rounds)
      float r0 = a0, r1 = a1, r2 = a2, r3 = a3;
      r0 += __shfl_xor(r0, 16); r1 += __shfl_xor(r1, 16);
      r2 += __shfl_xor(r2, 16); r3 += __shfl_xor(r3, 16);
      r0 += __shfl_xor(r0, 32); r1 += __shfl_xor(r1, 32);
      r2 += __shfl_xor(r2, 32); r3 += __shfl_xor(r3, 32);
      float v0 = fmaf(r0, dv, bl0), v1 = fmaf(r1, dv, bl1);
      float v2 = fmaf(r2, dv, bl2), v3 = fmaf(r3, dv, bl3);
      if (g == 0) {
        float4 st; st.x = v0; st.y = v1; st.z = v2; st.w = v3;
        *(float4*)(acc + ((size_t)row << 6) + fb) = st;
        sm0 += v0; sm1 += v1; sm2 += v2; sm3 += v3;
        sq0 = fmaf(v0, v0, sq0); sq1 = fmaf(v1, v1, sq1);
        sq2 = fmaf(v2, v2, sq2); sq3 = fmaf(v3, v3, sq3);
      }
    }
  }

  __shared__ float ls[4][DF], lss[4][DF];
  if (g == 0) {                      // 16 lanes cover all 64 features via fb quads
    float4 t1; t1.x = sm0; t1.y = sm1; t1.z = sm2; t1.w = sm3;
    float4 t2; t2.x = sq0; t2.y = sq1; t2.z = sq2; t2.w = sq3;
    *(float4*)&ls[wsub][fb] = t1;
    *(float4*)&lss[wsub][fb] = t2;
  }
  __syncthreads();
  if (threadIdx.x < DF) {
    int fi = threadIdx.x;
    float t1 = ls[0][fi] + ls[1][fi] + ls[2][fi] + ls[3][fi];
    float t2 = lss[0][fi] + lss[1][fi] + lss[2][fi] + lss[3][fi];
    int slot = (blockIdx.x & 63) * 128;   // 64-way spread kills same-line contention
    unsafeAtomicAdd(&statp[slot + fi], t1);
    unsafeAtomicAdd(&statp[slot + DF + fi], t2);
  }
}

__global__ void finalize_stats(const float* __restrict__ statp, float* __restrict__ stats,
                               const float* __restrict__ gamma,
                               const float* __restrict__ beta, int n) {
  int f = threadIdx.x;
  if (f >= DF) return;
  float s = 0.f, ss = 0.f;
#pragma unroll 4
  for (int c = 0; c < 64; c++) {
    s += statp[c * 128 + f];
    ss += statp[c * 128 + DF + f];
  }
  float mean = s / n;
  float var = ss / n - mean * mean;
  float rstd = rsqrtf(var + 1e-5f);
  float sc = gamma[f] * rstd;
  stats[128 + f] = sc;
  stats[192 + f] = beta[f] - mean * sc;
}

__global__ void bnapply(const float* __restrict__ acc, const float* __restrict__ stats,
                        const float* __restrict__ alpha_p, float* __restrict__ outb, int n) {
  int i = blockIdx.x * 4 + (threadIdx.x >> 6);
  if (i >= n) return;
  int f = threadIdx.x & 63;
  float y = acc[(size_t)i * DF + f] * stats[128 + f] + stats[192 + f];
  float a = alpha_p[0];
  y = (y >= 0.f) ? y : a * y;
  outb[(size_t)i * DF + f] = y;
}

extern "C" void kernel_launch(void* const* d_in, const int* in_sizes, int n_in,
                              void* d_out, int out_size, void* d_ws, size_t ws_size,
                              hipStream_t stream) {
  const float* x  = (const float*)d_in[0];
  const int* ei   = (const int*)d_in[1];
  const float* w  = (const float*)d_in[2];
  const float* W1 = (const float*)d_in[3];
  const float* b1 = (const float*)d_in[4];
  const float* g1 = (const float*)d_in[5];
  const float* be1= (const float*)d_in[6];
  const float* al1= (const float*)d_in[7];
  const float* W2 = (const float*)d_in[8];
  const float* b2 = (const float*)d_in[9];
  const float* g2 = (const float*)d_in[10];
  const float* be2= (const float*)d_in[11];
  const float* al2= (const float*)d_in[12];
  float* out = (float*)d_out;

  const int n = in_sizes[0] / DF;
  const int E = in_sizes[2];
  const size_t na = ((size_t)n + 255) & ~(size_t)255;
  const int NB = (n + BW - 1) >> BSH;
  const int nblk1 = (E + 1023) / 1024;
  const size_t ghsz = (((size_t)nblk1 * NB) + 3) & ~(size_t)3;
  const int tiles = (n + 15) / 16;
  const size_t pk2cap = (size_t)E + (size_t)NB * PADCAP + 64;

  // ---- workspace layout (4-byte units; int2 arrays 8B-aligned) ----
  float* wsf = (float*)d_ws;
  float* stats1 = wsf;                          // 256
  float* stats2 = stats1 + 256;                 // 256
  float* statp1 = stats2 + 256;                 // 8192 (64 spread copies x 128)
  float* statp2 = statp1 + 8192;                // 8192
  int*   btot   = (int*)(statp2 + 8192);        // 512
  int*   bstart = btot + 512;                   // 512 (NB+1 used)
  int*   bendp  = bstart + 512;                 // 512 (NB used)
  int*   rowptr = bendp + 512;                  // na + 4 (n+1 used)
  float* dinv   = (float*)(rowptr + na + 4);    // na
  int*   gh     = (int*)(dinv + na);            // ghsz
  int2*  pk2    = (int2*)(gh + ghsz);           // pk2cap records (8B each, padded CSR)
  int*   U      = (int*)(pk2 + pk2cap);         // overlay: pk1 (2E) | XL16+ACC
  int2*  pk1    = (int2*)U;
  u16*   XL16   = (u16*)U;                      // na*64 bf16 (after pass2)
  float* ACC    = (float*)(U + na * 32);        // na*64 fp32

  const int nb_nodes = (n + 3) / 4;
  const int nb_gemm  = 512;
  const int nb_agg   = (n + 15) / 16;           // wave = 4 rows, block = 16 rows

  hipMemsetAsync(stats1, 0, (512 + 16384) * sizeof(float), stream);

  // ---- CSR build (bucket sort, 8B records, padded per-node rowptr) ----
  prehist<<<nblk1, 256, 0, stream>>>(ei, gh, E, NB);
  scanA<<<NB, 256, 0, stream>>>(gh, btot, nblk1, NB);
  scanB<<<1, 256, 0, stream>>>(btot, bstart, rowptr, NB, n, E);
  pass1<<<nblk1, 256, 0, stream>>>(ei, w, gh, bstart, pk1, E, NB);
  pass2<<<NB, 256, 0, stream>>>(pk1, bstart, pk2, dinv, rowptr, bendp, n);

  // ---- layer 1 ----
  gemm_init<<<nb_gemm, 256, 0, stream>>>(x, W1, dinv, XL16, n, tiles);
  edge_agg6<<<nb_agg, 256, 0, stream>>>(pk2, rowptr, bendp, XL16, dinv, b1, ACC, statp1, n);
  finalize_stats<<<1, 64, 0, stream>>>(statp1, stats1, g1, be1, n);

  // ---- layer 2 ----
  gemm_bn_init<<<nb_gemm, 256, 0, stream>>>(ACC, stats1, al1, W2, dinv, XL16, n, tiles);
  edge_agg6<<<nb_agg, 256, 0, stream>>>(pk2, rowptr, bendp, XL16, dinv, b2, ACC, statp2, n);
  finalize_stats<<<1, 64, 0, stream>>>(statp2, stats2, g2, be2, n);
  bnapply<<<nb_nodes, 256, 0, stream>>>(ACC, stats2, al2, out, n);
}